// Round 4
// baseline (221.486 us; speedup 1.0000x reference)
//
#include <hip/hip_runtime.h>
#include <stdint.h>

// ---------------------------------------------------------------------------
// ATSS assigner, MI355X. B=16, M=64, A=33600 (levels 25600/6400/1600), TOPK=9.
// R4: R3 split (assign + streaming one-hot writer) with clang-native vec4
//     type for __builtin_nontemporal_store (HIP float4 is a class -> rejected).
// ---------------------------------------------------------------------------

constexpr int A_TOT = 33600;
constexpr int NB    = 16;
constexpr int NM    = 64;
constexpr int NCLS  = 80;
constexpr int NBA   = NB * A_TOT;          // 537600

typedef float vfloat4 __attribute__((ext_vector_type(4)));   // nt-store-able

// Anchor grid is analytic and exactly representable in fp32:
// level 0: stride 8,  160x160, half=20, area=1600
// level 1: stride 16,  80x80,  half=40, area=6400
// level 2: stride 32,  40x40,  half=80, area=25600
__device__ __forceinline__ void anchor_geom(int a, float& cx, float& cy,
                                            float& half, float& area) {
    if (a < 25600) {
        int row = a / 160, col = a - row * 160;
        cx = (col + 0.5f) * 8.0f;  cy = (row + 0.5f) * 8.0f;
        half = 20.0f; area = 1600.0f;
    } else if (a < 32000) {
        int j = a - 25600; int row = j / 80, col = j - row * 80;
        cx = (col + 0.5f) * 16.0f; cy = (row + 0.5f) * 16.0f;
        half = 40.0f; area = 6400.0f;
    } else {
        int j = a - 32000; int row = j / 40, col = j - row * 40;
        cx = (col + 0.5f) * 32.0f; cy = (row + 0.5f) * 32.0f;
        half = 80.0f; area = 25600.0f;
    }
}

// IoU with the reference's exact op order: ov / (area_g + area_a - ov + 1e-9)
__device__ __forceinline__ float iou_box(float gx1, float gy1, float gx2, float gy2,
                                         float areag, float cx, float cy,
                                         float half, float areaa) {
    float ax1 = cx - half, ay1 = cy - half, ax2 = cx + half, ay2 = cy + half;
    float ltx = fmaxf(gx1, ax1), lty = fmaxf(gy1, ay1);
    float rbx = fminf(gx2, ax2), rby = fminf(gy2, ay2);
    float w = fmaxf(rbx - ltx, 0.0f), h = fmaxf(rby - lty, 0.0f);
    float ov = w * h;
    return ov / (areag + areaa - ov + 1e-9f);
}

// Per-level exact top-9 by (dist, index) lex order over the 13x13 window
// around the gt center (window provably contains the true top-9; any outside
// point is dominated by >= 12 in-window points even after sqrt rounding).
// Key = (float_bits(d) << 32) | global_idx -> matches jax.lax.top_k order.
template <int START, int N1, int S>
__device__ __forceinline__ void window_level(int lane, float gcx, float gcy,
                                             uint64_t* cand_out /* 9 LDS slots */) {
    float tx = gcx / (float)S - 0.5f;
    float ty = gcy / (float)S - 0.5f;
    int c0 = (int)floorf(tx) - 6; c0 = min(max(c0, 0), N1 - 13);
    int r0 = (int)floorf(ty) - 6; r0 = min(max(r0, 0), N1 - 13);

    uint64_t k9[9];
#pragma unroll
    for (int i = 0; i < 9; ++i) k9[i] = ~0ull;

    for (int k = lane; k < 169; k += 64) {
        int wr = k / 13, wc = k - wr * 13;
        int row = r0 + wr, col = c0 + wc;
        float cx = (col + 0.5f) * (float)S;
        float cy = (row + 0.5f) * (float)S;
        float dx = gcx - cx, dy = gcy - cy;
        float d  = sqrtf(dx * dx + dy * dy);
        uint64_t key = ((uint64_t)__float_as_uint(d) << 32)
                     | (uint32_t)(START + row * N1 + col);
        if (key < k9[8]) {            // sorted-insert (keeps ascending)
            uint64_t x = key;
#pragma unroll
            for (int i = 0; i < 9; ++i) {
                if (x < k9[i]) { uint64_t t = k9[i]; k9[i] = x; x = t; }
            }
        }
    }

    // 9 rounds of wave-wide min; winner pops its head. Keys unique (index bits).
    for (int r = 0; r < 9; ++r) {
        unsigned long long v = (unsigned long long)k9[0];
#pragma unroll
        for (int off = 1; off < 64; off <<= 1) {
            unsigned long long o = __shfl_xor(v, off, 64);
            if (o < v) v = o;
        }
        if ((uint64_t)v == k9[0]) {
#pragma unroll
            for (int i = 0; i < 8; ++i) k9[i] = k9[i + 1];
            k9[8] = ~0ull;
        }
        if (lane == 0) cand_out[r] = (uint64_t)v;
    }
}

// One wave per (b,m): windowed top-9 per level, thr = mean+std(ddof=1) over
// the 27 candidate IoUs, scatter survivors into packed count/min-m.
__global__ __launch_bounds__(64) void atss_topk(
    const float* __restrict__ gt_bboxes,   // B*M*4
    const float* __restrict__ pad_mask,    // B*M
    uint32_t* __restrict__ packed)         // B*A: (count<<20)|sum_m
{
    int bm = blockIdx.x;
    if (pad_mask[bm] <= 0.0f) return;      // invalid gt: contributes nothing
    int b = bm >> 6, m = bm & 63;
    int lane = threadIdx.x;

    float4 g = ((const float4*)gt_bboxes)[bm];
    float gcx = (g.x + g.z) * 0.5f, gcy = (g.y + g.w) * 0.5f;
    float areag = (g.z - g.x) * (g.w - g.y);

    __shared__ uint64_t cand[27];
    __shared__ float    iou_s[27];
    __shared__ int      ok_s[27];

    window_level<0,     160,  8>(lane, gcx, gcy, cand + 0);
    window_level<25600,  80, 16>(lane, gcx, gcy, cand + 9);
    window_level<32000,  40, 32>(lane, gcx, gcy, cand + 18);
    __syncthreads();

    int aidx = 0; float iou = 0.0f;
    if (lane < 27) {
        aidx = (int)(cand[lane] & 0xffffffffu);
        float cx, cy, half, areaa;
        anchor_geom(aidx, cx, cy, half, areaa);
        iou = iou_box(g.x, g.y, g.z, g.w, areag, cx, cy, half, areaa);
        // is_in_gts: anchor center strictly inside gt (min(l,t,r,b) > 1e-9)
        float l = cx - g.x, t = cy - g.y, r = g.z - cx, btm = g.w - cy;
        float mn = fminf(fminf(l, t), fminf(r, btm));
        iou_s[lane] = iou;
        ok_s[lane]  = (mn > 1e-9f) ? 1 : 0;
    }
    __syncthreads();

    // thr = mean + std(ddof=1); same sequential order as the passing kernels
    float sum = 0.0f;
#pragma unroll
    for (int i = 0; i < 27; ++i) sum += iou_s[i];
    float mean = sum / 27.0f;
    float var = 0.0f;
#pragma unroll
    for (int i = 0; i < 27; ++i) { float d = iou_s[i] - mean; var += d * d; }
    float thr = mean + sqrtf(var / 26.0f);

    if (lane < 27 && ok_s[lane] && iou > thr) {
        // count in bits 20+, sum of m in low 20 bits. If count==1 the low
        // bits are exactly the single contributor's m. max sum 56*63 < 2^20.
        atomicAdd(&packed[b * A_TOT + aidx], (1u << 20) | (uint32_t)m);
    }
}

// One thread per (b,a): resolve assignment, write labels (float out + int ws)
// and bboxes. 13 MB of nontemporal stores; the divergent contested path
// lives only here, away from the big streaming kernel.
__global__ __launch_bounds__(256) void atss_assign(
    const float* __restrict__ gt_bboxes,   // B*M*4
    const int*   __restrict__ gt_labels,   // B*M
    const uint32_t* __restrict__ packed,
    float* __restrict__ out,
    int*   __restrict__ labels_i)          // B*A ints for the score writer
{
    int tid = blockIdx.x * 256 + threadIdx.x;   // NBA divisible by 256
    int b = tid / A_TOT;
    int a = tid - b * A_TOT;

    uint32_t pk = packed[tid];
    int c = (int)(pk >> 20);
    int gidx = 0;
    if (c == 1) {
        gidx = (int)(pk & 0xfffffu);
    } else if (c > 1) {
        // contested anchor: reference replaces row with is_max_iou (argmax of
        // iou over all 64 gts incl. padded; first occurrence on ties)
        float cx, cy, half, areaa;
        anchor_geom(a, cx, cy, half, areaa);
        const float4* gb = (const float4*)(gt_bboxes) + b * NM;
        float best = -1.0f; int bi = 0;
        for (int mm = 0; mm < NM; ++mm) {
            float4 g = gb[mm];
            float areag = (g.z - g.x) * (g.w - g.y);
            float iou = iou_box(g.x, g.y, g.z, g.w, areag, cx, cy, half, areaa);
            if (iou > best) { best = iou; bi = mm; }
        }
        gidx = bi;
    }

    int label = (c > 0) ? gt_labels[b * NM + gidx] : NCLS;
    labels_i[tid] = label;                 // normal store (L2-resident for B)
    __builtin_nontemporal_store((float)label, out + tid);      // labels region
    const vfloat4* gb4 = (const vfloat4*)gt_bboxes;
    vfloat4 gsel = gb4[b * NM + gidx];
    __builtin_nontemporal_store(gsel, (vfloat4*)(out + NBA) + tid);  // bboxes
}

// Pure streaming one-hot writer: 172 MB, 8 independent nt float4 stores per
// thread, one L1-cached int load each. Tiny VGPR footprint -> max occupancy.
__global__ __launch_bounds__(256) void atss_scores(
    const int* __restrict__ labels_i,
    float* __restrict__ scores)            // out + NBA*5, NBA*80 floats
{
    vfloat4* s4 = (vfloat4*)scores;
    int k0 = blockIdx.x * 2048 + threadIdx.x;   // 2048 float4 per block
#pragma unroll
    for (int i = 0; i < 8; ++i) {
        int k  = k0 + i * 256;
        int al = k / 20;                    // anchor row (80 cls = 20 float4)
        int c4 = k - al * 20;
        int lab = labels_i[al];
        int base = c4 * 4;
        vfloat4 v;
        v.x = (base + 0 == lab) ? 1.0f : 0.0f;
        v.y = (base + 1 == lab) ? 1.0f : 0.0f;
        v.z = (base + 2 == lab) ? 1.0f : 0.0f;
        v.w = (base + 3 == lab) ? 1.0f : 0.0f;
        __builtin_nontemporal_store(v, s4 + k);
    }
}

__global__ void atss_init(uint32_t* __restrict__ packed) {
    int i = blockIdx.x * 256 + threadIdx.x;
    if (i < NBA) packed[i] = 0u;
}

extern "C" void kernel_launch(void* const* d_in, const int* in_sizes, int n_in,
                              void* d_out, int out_size, void* d_ws, size_t ws_size,
                              hipStream_t stream) {
    // inputs: 0 anchor_bboxes (unused, analytic grid), 1 num_anchors_list (fixed),
    //         2 gt_labels, 3 gt_bboxes, 4 pad_gt_mask, 5 bg_index (fixed 80)
    const int*   gt_labels = (const int*)d_in[2];
    const float* gt_bboxes = (const float*)d_in[3];
    const float* pad_mask  = (const float*)d_in[4];
    float* out = (float*)d_out;

    uint32_t* packed   = (uint32_t*)d_ws;
    int*      labels_i = (int*)d_ws + NBA;

    atss_init<<<(NBA + 255) / 256, 256, 0, stream>>>(packed);

    atss_topk<<<NB * NM, 64, 0, stream>>>(gt_bboxes, pad_mask, packed);

    atss_assign<<<NBA / 256, 256, 0, stream>>>(
        gt_bboxes, gt_labels, packed, out, labels_i);

    // scores region: NBA*80 floats = 10,752,000 float4 = 5250 blocks * 2048
    atss_scores<<<(NBA * 20) / 2048, 256, 0, stream>>>(
        labels_i, out + (size_t)NBA * 5);
}

// Round 5
// 209.004 us; speedup vs baseline: 1.0597x; 1.0597x over previous
//
#include <hip/hip_runtime.h>
#include <stdint.h>

// ---------------------------------------------------------------------------
// ATSS assigner, MI355X. B=16, M=64, A=33600 (levels 25600/6400/1600), TOPK=9.
// R5: topk pops the three levels' top-9 with interleaved butterflies (3-way
//     ILP on the shuffle dep chains); init via hipMemsetAsync node; fused
//     finalize (R2 structure, plain stores).
// ---------------------------------------------------------------------------

constexpr int A_TOT = 33600;
constexpr int NB    = 16;
constexpr int NM    = 64;
constexpr int NCLS  = 80;
constexpr int NBA   = NB * A_TOT;          // 537600

// Anchor grid is analytic and exactly representable in fp32:
// level 0: stride 8,  160x160, half=20, area=1600
// level 1: stride 16,  80x80,  half=40, area=6400
// level 2: stride 32,  40x40,  half=80, area=25600
__device__ __forceinline__ void anchor_geom(int a, float& cx, float& cy,
                                            float& half, float& area) {
    if (a < 25600) {
        int row = a / 160, col = a - row * 160;
        cx = (col + 0.5f) * 8.0f;  cy = (row + 0.5f) * 8.0f;
        half = 20.0f; area = 1600.0f;
    } else if (a < 32000) {
        int j = a - 25600; int row = j / 80, col = j - row * 80;
        cx = (col + 0.5f) * 16.0f; cy = (row + 0.5f) * 16.0f;
        half = 40.0f; area = 6400.0f;
    } else {
        int j = a - 32000; int row = j / 40, col = j - row * 40;
        cx = (col + 0.5f) * 32.0f; cy = (row + 0.5f) * 32.0f;
        half = 80.0f; area = 25600.0f;
    }
}

// IoU with the reference's exact op order: ov / (area_g + area_a - ov + 1e-9)
__device__ __forceinline__ float iou_box(float gx1, float gy1, float gx2, float gy2,
                                         float areag, float cx, float cy,
                                         float half, float areaa) {
    float ax1 = cx - half, ay1 = cy - half, ax2 = cx + half, ay2 = cy + half;
    float ltx = fmaxf(gx1, ax1), lty = fmaxf(gy1, ay1);
    float rbx = fminf(gx2, ax2), rby = fminf(gy2, ay2);
    float w = fmaxf(rbx - ltx, 0.0f), h = fmaxf(rby - lty, 0.0f);
    float ov = w * h;
    return ov / (areag + areaa - ov + 1e-9f);
}

// Per-level scan: per-lane sorted-9 candidate list over the 13x13 window
// around the gt center (window provably contains the true top-9; any outside
// point is dominated by >= 12 in-window points even after sqrt rounding).
// Key = (float_bits(d) << 32) | global_idx -> matches jax.lax.top_k order.
template <int START, int N1, int S>
__device__ __forceinline__ void window_scan(int lane, float gcx, float gcy,
                                            uint64_t k9[9]) {
    float tx = gcx / (float)S - 0.5f;
    float ty = gcy / (float)S - 0.5f;
    int c0 = (int)floorf(tx) - 6; c0 = min(max(c0, 0), N1 - 13);
    int r0 = (int)floorf(ty) - 6; r0 = min(max(r0, 0), N1 - 13);

#pragma unroll
    for (int i = 0; i < 9; ++i) k9[i] = ~0ull;

    for (int k = lane; k < 169; k += 64) {
        int wr = k / 13, wc = k - wr * 13;
        int row = r0 + wr, col = c0 + wc;
        float cx = (col + 0.5f) * (float)S;
        float cy = (row + 0.5f) * (float)S;
        float dx = gcx - cx, dy = gcy - cy;
        float d  = sqrtf(dx * dx + dy * dy);
        uint64_t key = ((uint64_t)__float_as_uint(d) << 32)
                     | (uint32_t)(START + row * N1 + col);
        if (key < k9[8]) {            // sorted-insert (keeps ascending)
            uint64_t x = key;
#pragma unroll
            for (int i = 0; i < 9; ++i) {
                if (x < k9[i]) { uint64_t t = k9[i]; k9[i] = x; x = t; }
            }
        }
    }
}

// One wave per (b,m): windowed top-9 per level (3 levels popped with
// interleaved butterflies for ILP), thr = mean+std(ddof=1) over the 27
// candidate IoUs, scatter survivors into packed count/sum-m.
__global__ __launch_bounds__(64) void atss_topk(
    const float* __restrict__ gt_bboxes,   // B*M*4
    const float* __restrict__ pad_mask,    // B*M
    uint32_t* __restrict__ packed)         // B*A: (count<<20)|sum_m
{
    int bm = blockIdx.x;
    if (pad_mask[bm] <= 0.0f) return;      // invalid gt: contributes nothing
    int b = bm >> 6, m = bm & 63;
    int lane = threadIdx.x;

    float4 g = ((const float4*)gt_bboxes)[bm];
    float gcx = (g.x + g.z) * 0.5f, gcy = (g.y + g.w) * 0.5f;
    float areag = (g.z - g.x) * (g.w - g.y);

    __shared__ uint64_t cand[27];
    __shared__ float    iou_s[27];
    __shared__ int      ok_s[27];

    uint64_t L0[9], L1[9], L2[9];
    window_scan<0,     160,  8>(lane, gcx, gcy, L0);
    window_scan<25600,  80, 16>(lane, gcx, gcy, L1);
    window_scan<32000,  40, 32>(lane, gcx, gcy, L2);

    // 9 pop rounds; the three levels' 6-step shuffle-min chains are
    // independent -> issue interleaved (3-way ILP). Keys unique per level
    // (index bits), so exactly one lane pops its head per level per round.
    for (int r = 0; r < 9; ++r) {
        unsigned long long va = (unsigned long long)L0[0];
        unsigned long long vb = (unsigned long long)L1[0];
        unsigned long long vc = (unsigned long long)L2[0];
#pragma unroll
        for (int off = 1; off < 64; off <<= 1) {
            unsigned long long oa = __shfl_xor(va, off, 64);
            unsigned long long ob = __shfl_xor(vb, off, 64);
            unsigned long long oc = __shfl_xor(vc, off, 64);
            if (oa < va) va = oa;
            if (ob < vb) vb = ob;
            if (oc < vc) vc = oc;
        }
        if ((uint64_t)va == L0[0]) {
#pragma unroll
            for (int i = 0; i < 8; ++i) L0[i] = L0[i + 1];
            L0[8] = ~0ull;
        }
        if ((uint64_t)vb == L1[0]) {
#pragma unroll
            for (int i = 0; i < 8; ++i) L1[i] = L1[i + 1];
            L1[8] = ~0ull;
        }
        if ((uint64_t)vc == L2[0]) {
#pragma unroll
            for (int i = 0; i < 8; ++i) L2[i] = L2[i + 1];
            L2[8] = ~0ull;
        }
        if (lane == 0) {
            cand[r]      = (uint64_t)va;
            cand[9 + r]  = (uint64_t)vb;
            cand[18 + r] = (uint64_t)vc;
        }
    }
    __syncthreads();

    int aidx = 0; float iou = 0.0f;
    if (lane < 27) {
        aidx = (int)(cand[lane] & 0xffffffffu);
        float cx, cy, half, areaa;
        anchor_geom(aidx, cx, cy, half, areaa);
        iou = iou_box(g.x, g.y, g.z, g.w, areag, cx, cy, half, areaa);
        // is_in_gts: anchor center strictly inside gt (min(l,t,r,b) > 1e-9)
        float l = cx - g.x, t = cy - g.y, r = g.z - cx, btm = g.w - cy;
        float mn = fminf(fminf(l, t), fminf(r, btm));
        iou_s[lane] = iou;
        ok_s[lane]  = (mn > 1e-9f) ? 1 : 0;
    }
    __syncthreads();

    // thr = mean + std(ddof=1); same sequential order as the passing kernels
    float sum = 0.0f;
#pragma unroll
    for (int i = 0; i < 27; ++i) sum += iou_s[i];
    float mean = sum / 27.0f;
    float var = 0.0f;
#pragma unroll
    for (int i = 0; i < 27; ++i) { float d = iou_s[i] - mean; var += d * d; }
    float thr = mean + sqrtf(var / 26.0f);

    if (lane < 27 && ok_s[lane] && iou > thr) {
        // count in bits 20+, sum of m in low 20 bits. If count==1 the low
        // bits are exactly the single contributor's m. max sum 56*63 < 2^20.
        atomicAdd(&packed[b * A_TOT + aidx], (1u << 20) | (uint32_t)m);
    }
}

// One thread per (b,a): resolve assignment, write labels + bboxes + the FULL
// one-hot score row (coalesced float4 via LDS-staged labels) in one pass.
__global__ __launch_bounds__(256) void atss_finalize(
    const float* __restrict__ gt_bboxes,   // B*M*4
    const int*   __restrict__ gt_labels,   // B*M
    const uint32_t* __restrict__ packed,
    float* __restrict__ out)
{
    int tid = blockIdx.x * 256 + threadIdx.x;   // NBA divisible by 256
    int b = tid / A_TOT;
    int a = tid - b * A_TOT;

    uint32_t pk = packed[tid];
    int c = (int)(pk >> 20);
    int gidx = 0;
    if (c == 1) {
        gidx = (int)(pk & 0xfffffu);
    } else if (c > 1) {
        // contested anchor: reference replaces row with is_max_iou (argmax of
        // iou over all 64 gts incl. padded; first occurrence on ties)
        float cx, cy, half, areaa;
        anchor_geom(a, cx, cy, half, areaa);
        const float4* gb = (const float4*)(gt_bboxes) + b * NM;
        float best = -1.0f; int bi = 0;
        for (int mm = 0; mm < NM; ++mm) {
            float4 g = gb[mm];
            float areag = (g.z - g.x) * (g.w - g.y);
            float iou = iou_box(g.x, g.y, g.z, g.w, areag, cx, cy, half, areaa);
            if (iou > best) { best = iou; bi = mm; }
        }
        gidx = bi;
    }

    int label = (c > 0) ? gt_labels[b * NM + gidx] : NCLS;
    out[tid] = (float)label;                                   // labels region
    float4 gsel = ((const float4*)gt_bboxes)[b * NM + gidx];
    ((float4*)(out + NBA))[tid] = gsel;                        // bbox region

    // ---- full one-hot score rows for this block's 256 anchors, coalesced ----
    __shared__ int lab_s[256];
    lab_s[threadIdx.x] = label;
    __syncthreads();

    float4* sc4 = (float4*)(out + (size_t)NBA * 5)
                + (size_t)blockIdx.x * (256 * 20);   // 20 float4 per anchor
#pragma unroll
    for (int i = 0; i < 20; ++i) {
        int k  = threadIdx.x + i * 256;     // 0..5119, coalesced
        int al = k / 20;                    // local anchor
        int c4 = k - al * 20;               // which float4 of the 80 classes
        int lab = lab_s[al];
        int base = c4 * 4;
        float4 v;
        v.x = (base + 0 == lab) ? 1.0f : 0.0f;
        v.y = (base + 1 == lab) ? 1.0f : 0.0f;
        v.z = (base + 2 == lab) ? 1.0f : 0.0f;
        v.w = (base + 3 == lab) ? 1.0f : 0.0f;
        sc4[k] = v;
    }
}

extern "C" void kernel_launch(void* const* d_in, const int* in_sizes, int n_in,
                              void* d_out, int out_size, void* d_ws, size_t ws_size,
                              hipStream_t stream) {
    // inputs: 0 anchor_bboxes (unused, analytic grid), 1 num_anchors_list (fixed),
    //         2 gt_labels, 3 gt_bboxes, 4 pad_gt_mask, 5 bg_index (fixed 80)
    const int*   gt_labels = (const int*)d_in[2];
    const float* gt_bboxes = (const float*)d_in[3];
    const float* pad_mask  = (const float*)d_in[4];
    float* out = (float*)d_out;

    uint32_t* packed = (uint32_t*)d_ws;

    // graph-native memset node instead of an init kernel dispatch
    hipMemsetAsync(packed, 0, (size_t)NBA * sizeof(uint32_t), stream);

    atss_topk<<<NB * NM, 64, 0, stream>>>(gt_bboxes, pad_mask, packed);

    atss_finalize<<<NBA / 256, 256, 0, stream>>>(
        gt_bboxes, gt_labels, packed, out);
}

// Round 6
// 198.491 us; speedup vs baseline: 1.1158x; 1.0530x over previous
//
#include <hip/hip_runtime.h>
#include <stdint.h>

// ---------------------------------------------------------------------------
// ATSS assigner, MI355X. B=16, M=64, A=33600 (levels 25600/6400/1600), TOPK=9.
// R6: rank-based top-9 over a 6x6 window (one key per lane, parallel rank
//     loop in LDS) -- removes the 27 sequential wave-min extraction rounds.
//     Finalize / memset unchanged from R5 (passing, bit-exact).
// ---------------------------------------------------------------------------

constexpr int A_TOT = 33600;
constexpr int NB    = 16;
constexpr int NM    = 64;
constexpr int NCLS  = 80;
constexpr int NBA   = NB * A_TOT;          // 537600

// Anchor grid is analytic and exactly representable in fp32:
// level 0: stride 8,  160x160, half=20, area=1600
// level 1: stride 16,  80x80,  half=40, area=6400
// level 2: stride 32,  40x40,  half=80, area=25600
__device__ __forceinline__ void anchor_geom(int a, float& cx, float& cy,
                                            float& half, float& area) {
    if (a < 25600) {
        int row = a / 160, col = a - row * 160;
        cx = (col + 0.5f) * 8.0f;  cy = (row + 0.5f) * 8.0f;
        half = 20.0f; area = 1600.0f;
    } else if (a < 32000) {
        int j = a - 25600; int row = j / 80, col = j - row * 80;
        cx = (col + 0.5f) * 16.0f; cy = (row + 0.5f) * 16.0f;
        half = 40.0f; area = 6400.0f;
    } else {
        int j = a - 32000; int row = j / 40, col = j - row * 40;
        cx = (col + 0.5f) * 32.0f; cy = (row + 0.5f) * 32.0f;
        half = 80.0f; area = 25600.0f;
    }
}

// IoU with the reference's exact op order: ov / (area_g + area_a - ov + 1e-9)
__device__ __forceinline__ float iou_box(float gx1, float gy1, float gx2, float gy2,
                                         float areag, float cx, float cy,
                                         float half, float areaa) {
    float ax1 = cx - half, ay1 = cy - half, ax2 = cx + half, ay2 = cy + half;
    float ltx = fmaxf(gx1, ax1), lty = fmaxf(gy1, ay1);
    float rbx = fminf(gx2, ax2), rby = fminf(gy2, ay2);
    float w = fmaxf(rbx - ltx, 0.0f), h = fmaxf(rby - lty, 0.0f);
    float ov = w * h;
    return ov / (areag + areaa - ov + 1e-9f);
}

// Rank-based exact top-9 over the 6x6 window around the gt center.
// Containment proof: any grid point outside the (clamped) 6x6 window is
// >= 3 cells away in x or y; the window's inner 4x4 block provides >= 16
// points at dist <= sqrt(8) < 3 cells (margin >= 0.17 cells >> fp32 ulp),
// and in hard-clamped border cases the nearest 3x3 block still strictly
// dominates -- so the true top-9 always lies inside the window.
// Key = (float_bits(d) << 32) | global_idx: lex order == jax.lax.top_k
// order (lower index wins ties). Lane i (i<36) owns one key; its rank is
// computed with a fully parallel 36-compare loop (uniform LDS address per
// step -> broadcast). Lanes with rank<9 scatter cand[rank]=key, which
// reproduces EXACTLY the ascending slot order of the previous kernels.
template <int START, int N1, int S>
__device__ __forceinline__ void window_rank(int lane, float gcx, float gcy,
                                            uint64_t* keys36,
                                            uint64_t* cand_out /* 9 slots */) {
    float tx = gcx / (float)S - 0.5f;
    float ty = gcy / (float)S - 0.5f;
    int c0 = (int)floorf(tx) - 2; c0 = min(max(c0, 0), N1 - 6);
    int r0 = (int)floorf(ty) - 2; r0 = min(max(r0, 0), N1 - 6);

    uint64_t mykey = ~0ull;
    if (lane < 36) {
        int wr = lane / 6, wc = lane - wr * 6;
        int row = r0 + wr, col = c0 + wc;
        float cx = (col + 0.5f) * (float)S;
        float cy = (row + 0.5f) * (float)S;
        float dx = gcx - cx, dy = gcy - cy;
        float d  = sqrtf(dx * dx + dy * dy);
        mykey = ((uint64_t)__float_as_uint(d) << 32)
              | (uint32_t)(START + row * N1 + col);
        keys36[lane] = mykey;
    }
    __syncthreads();                       // single wave: waitcnt + s_barrier

    if (lane < 36) {
        int rank = 0;
#pragma unroll
        for (int j = 0; j < 36; ++j)
            rank += (keys36[j] < mykey) ? 1 : 0;
        if (rank < 9) cand_out[rank] = mykey;
    }
    __syncthreads();
}

// One wave per (b,m): 6x6 rank-select per level, thr = mean+std(ddof=1) over
// the 27 candidate IoUs, scatter survivors into packed count/sum-m.
__global__ __launch_bounds__(64) void atss_topk(
    const float* __restrict__ gt_bboxes,   // B*M*4
    const float* __restrict__ pad_mask,    // B*M
    uint32_t* __restrict__ packed)         // B*A: (count<<20)|sum_m
{
    int bm = blockIdx.x;
    if (pad_mask[bm] <= 0.0f) return;      // invalid gt: contributes nothing
    int b = bm >> 6, m = bm & 63;
    int lane = threadIdx.x;

    float4 g = ((const float4*)gt_bboxes)[bm];
    float gcx = (g.x + g.z) * 0.5f, gcy = (g.y + g.w) * 0.5f;
    float areag = (g.z - g.x) * (g.w - g.y);

    __shared__ uint64_t keys36[36];
    __shared__ uint64_t cand[27];
    __shared__ float    iou_s[27];
    __shared__ int      ok_s[27];

    window_rank<0,     160,  8>(lane, gcx, gcy, keys36, cand + 0);
    window_rank<25600,  80, 16>(lane, gcx, gcy, keys36, cand + 9);
    window_rank<32000,  40, 32>(lane, gcx, gcy, keys36, cand + 18);

    int aidx = 0; float iou = 0.0f;
    if (lane < 27) {
        aidx = (int)(cand[lane] & 0xffffffffu);
        float cx, cy, half, areaa;
        anchor_geom(aidx, cx, cy, half, areaa);
        iou = iou_box(g.x, g.y, g.z, g.w, areag, cx, cy, half, areaa);
        // is_in_gts: anchor center strictly inside gt (min(l,t,r,b) > 1e-9)
        float l = cx - g.x, t = cy - g.y, r = g.z - cx, btm = g.w - cy;
        float mn = fminf(fminf(l, t), fminf(r, btm));
        iou_s[lane] = iou;
        ok_s[lane]  = (mn > 1e-9f) ? 1 : 0;
    }
    __syncthreads();

    // thr = mean + std(ddof=1); same sequential order as the passing kernels
    float sum = 0.0f;
#pragma unroll
    for (int i = 0; i < 27; ++i) sum += iou_s[i];
    float mean = sum / 27.0f;
    float var = 0.0f;
#pragma unroll
    for (int i = 0; i < 27; ++i) { float d = iou_s[i] - mean; var += d * d; }
    float thr = mean + sqrtf(var / 26.0f);

    if (lane < 27 && ok_s[lane] && iou > thr) {
        // count in bits 20+, sum of m in low 20 bits. If count==1 the low
        // bits are exactly the single contributor's m. max sum 56*63 < 2^20.
        atomicAdd(&packed[b * A_TOT + aidx], (1u << 20) | (uint32_t)m);
    }
}

// One thread per (b,a): resolve assignment, write labels + bboxes + the FULL
// one-hot score row (coalesced float4 via LDS-staged labels) in one pass.
__global__ __launch_bounds__(256) void atss_finalize(
    const float* __restrict__ gt_bboxes,   // B*M*4
    const int*   __restrict__ gt_labels,   // B*M
    const uint32_t* __restrict__ packed,
    float* __restrict__ out)
{
    int tid = blockIdx.x * 256 + threadIdx.x;   // NBA divisible by 256
    int b = tid / A_TOT;
    int a = tid - b * A_TOT;

    uint32_t pk = packed[tid];
    int c = (int)(pk >> 20);
    int gidx = 0;
    if (c == 1) {
        gidx = (int)(pk & 0xfffffu);
    } else if (c > 1) {
        // contested anchor: reference replaces row with is_max_iou (argmax of
        // iou over all 64 gts incl. padded; first occurrence on ties)
        float cx, cy, half, areaa;
        anchor_geom(a, cx, cy, half, areaa);
        const float4* gb = (const float4*)(gt_bboxes) + b * NM;
        float best = -1.0f; int bi = 0;
        for (int mm = 0; mm < NM; ++mm) {
            float4 g = gb[mm];
            float areag = (g.z - g.x) * (g.w - g.y);
            float iou = iou_box(g.x, g.y, g.z, g.w, areag, cx, cy, half, areaa);
            if (iou > best) { best = iou; bi = mm; }
        }
        gidx = bi;
    }

    int label = (c > 0) ? gt_labels[b * NM + gidx] : NCLS;
    out[tid] = (float)label;                                   // labels region
    float4 gsel = ((const float4*)gt_bboxes)[b * NM + gidx];
    ((float4*)(out + NBA))[tid] = gsel;                        // bbox region

    // ---- full one-hot score rows for this block's 256 anchors, coalesced ----
    __shared__ int lab_s[256];
    lab_s[threadIdx.x] = label;
    __syncthreads();

    float4* sc4 = (float4*)(out + (size_t)NBA * 5)
                + (size_t)blockIdx.x * (256 * 20);   // 20 float4 per anchor
#pragma unroll
    for (int i = 0; i < 20; ++i) {
        int k  = threadIdx.x + i * 256;     // 0..5119, coalesced
        int al = k / 20;                    // local anchor
        int c4 = k - al * 20;               // which float4 of the 80 classes
        int lab = lab_s[al];
        int base = c4 * 4;
        float4 v;
        v.x = (base + 0 == lab) ? 1.0f : 0.0f;
        v.y = (base + 1 == lab) ? 1.0f : 0.0f;
        v.z = (base + 2 == lab) ? 1.0f : 0.0f;
        v.w = (base + 3 == lab) ? 1.0f : 0.0f;
        sc4[k] = v;
    }
}

extern "C" void kernel_launch(void* const* d_in, const int* in_sizes, int n_in,
                              void* d_out, int out_size, void* d_ws, size_t ws_size,
                              hipStream_t stream) {
    // inputs: 0 anchor_bboxes (unused, analytic grid), 1 num_anchors_list (fixed),
    //         2 gt_labels, 3 gt_bboxes, 4 pad_gt_mask, 5 bg_index (fixed 80)
    const int*   gt_labels = (const int*)d_in[2];
    const float* gt_bboxes = (const float*)d_in[3];
    const float* pad_mask  = (const float*)d_in[4];
    float* out = (float*)d_out;

    uint32_t* packed = (uint32_t*)d_ws;

    // graph-native memset node instead of an init kernel dispatch
    hipMemsetAsync(packed, 0, (size_t)NBA * sizeof(uint32_t), stream);

    atss_topk<<<NB * NM, 64, 0, stream>>>(gt_bboxes, pad_mask, packed);

    atss_finalize<<<NBA / 256, 256, 0, stream>>>(
        gt_bboxes, gt_labels, packed, out);
}